// Round 5
// baseline (9912.525 us; speedup 1.0000x reference)
//
#include <hip/hip_runtime.h>
#include <cstdint>
#include <cstddef>

// Problem dims
#define TT 512   // timesteps
#define BB 32    // batch
#define II 512   // input dim
#define HH 1024  // hidden dim
#define OO 256   // output dim
#define GG 4096  // 4*H

typedef __attribute__((ext_vector_type(8))) short short8;
typedef __attribute__((ext_vector_type(4))) float f32x4;

__device__ __forceinline__ unsigned short f2bf(float f) {
  unsigned u = __float_as_uint(f);
  u = (u + 0x7FFFu + ((u >> 16) & 1u)) >> 16;  // RNE truncation (inputs finite)
  return (unsigned short)u;
}
__device__ __forceinline__ float bf2f(unsigned short s) {
  return __uint_as_float(((unsigned)s) << 16);
}
__device__ __forceinline__ short8 pack8(f32x4 lo, f32x4 hi) {
  short8 v;
  v[0] = (short)f2bf(lo[0]); v[1] = (short)f2bf(lo[1]);
  v[2] = (short)f2bf(lo[2]); v[3] = (short)f2bf(lo[3]);
  v[4] = (short)f2bf(hi[0]); v[5] = (short)f2bf(hi[1]);
  v[6] = (short)f2bf(hi[2]); v[7] = (short)f2bf(hi[3]);
  return v;
}

// ---------- fp32 -> bf16 bulk convert (8 elems/thread) ----------
__global__ __launch_bounds__(256) void k_convert(const float* __restrict__ in,
                                                 unsigned short* __restrict__ out,
                                                 int n8) {
  int i = blockIdx.x * 256 + threadIdx.x;
  if (i >= n8) return;
  const f32x4* p = (const f32x4*)in + (size_t)i * 2;
  f32x4 a = p[0], b = p[1];
  *((short8*)out + i) = pack8(a, b);
}

// ---------- xg[t][g][b] = dot(x[b][t][:], W_ih[g][:]) + b_ih[g] + b_hh[g] ----------
// grid (64 gtiles, 512 t), 256 thr = 4 waves; wave = 16 g-rows x 32 b (2 N-tiles), K=512
__global__ __launch_bounds__(256) void k_xg(const unsigned short* __restrict__ xb,
                                            const unsigned short* __restrict__ wb,
                                            const float* __restrict__ bih,
                                            const float* __restrict__ bhh,
                                            unsigned short* __restrict__ xg) {
  int t = blockIdx.y;
  int g0 = blockIdx.x * 64;
  int wave = threadIdx.x >> 6, lane = threadIdx.x & 63;
  int lr = lane & 15, ko = lane >> 4;
  int rowA = g0 + wave * 16 + lr;        // W_ih row this lane loads (A row)
  int rD = g0 + wave * 16 + ko * 4;      // first D row this lane owns
  f32x4 bias = *(const f32x4*)(bih + rD);
  bias += *(const f32x4*)(bhh + rD);
  f32x4 acc0 = bias, acc1 = bias;
  const short8* arow = (const short8*)(wb + (size_t)rowA * II);
#pragma unroll
  for (int ks = 0; ks < 16; ++ks) {
    int k = ks * 32 + ko * 8;
    short8 a = arow[k >> 3];
    short8 b0 = *(const short8*)(xb + ((size_t)lr * TT + t) * II + k);
    short8 b1 = *(const short8*)(xb + ((size_t)(lr + 16) * TT + t) * II + k);
    acc0 = __builtin_amdgcn_mfma_f32_16x16x32_bf16(a, b0, acc0, 0, 0, 0);
    acc1 = __builtin_amdgcn_mfma_f32_16x16x32_bf16(a, b1, acc1, 0, 0, 0);
  }
  size_t base = (size_t)t * GG * BB;
#pragma unroll
  for (int q = 0; q < 4; ++q) {
    xg[base + (size_t)(rD + q) * BB + lr] = f2bf(acc0[q]);
    xg[base + (size_t)(rD + q) * BB + 16 + lr] = f2bf(acc1[q]);
  }
}

// ---------- grid barrier: zero-cache-maintenance version ----------
// All cross-block data (hbuf + flags) moves via relaxed agent-scope atomics
// (sc1: straight to/from the coherent point, L3). So the barrier needs NO
// wbl2 release writeback and NO acquire invalidate:
//   writer: s_waitcnt vmcnt(0) (h stores complete at L3) -> syncthreads ->
//           one relaxed flag store
//   reader: relaxed poll; compiler-only fence; syncthreads
__device__ __forceinline__ void gridbar(unsigned* flags, int p, unsigned gen, int tid) {
  asm volatile("s_waitcnt vmcnt(0)" ::: "memory");
  __syncthreads();
  if (tid == 0)
    __hip_atomic_store(flags + p, gen, __ATOMIC_RELAXED, __HIP_MEMORY_SCOPE_AGENT);
  if (tid < 64) {
    int it = 0;
    for (;;) {
      unsigned v = __hip_atomic_load(flags + tid, __ATOMIC_RELAXED, __HIP_MEMORY_SCOPE_AGENT);
      if (v >= gen) break;
      __builtin_amdgcn_s_sleep(1);
      if (++it > (1 << 24)) break;  // hang-safety: break instead of deadlock
    }
  }
  asm volatile("" ::: "memory");  // compiler fence only: no reordering, 0 instrs
  __syncthreads();
}

union Q2S { unsigned long long q[2]; short8 s; };

// ---------- persistent LSTM scan ----------
// 64 blocks x 512 thr (8 waves). Block p owns h-cols j0=p*16..+15 (64 W_hh rows).
// Wave (m = gate, n = batch-half) keeps its W_hh A-frags in registers (32x short8).
// Per step: B-frags (h bf16) read from the L3-coherent double buffer via relaxed
// agent atomic loads, 32 mfma/wave, gate exchange via LDS, fp32 activations,
// h published via packed relaxed agent atomic dword stores. One barrier/step.
__global__ __launch_bounds__(512, 2) void k_scan(const float* __restrict__ whh,
                                                 const unsigned short* __restrict__ xg,
                                                 const float* __restrict__ h0,
                                                 const float* __restrict__ c0,
                                                 unsigned short* __restrict__ hbuf,
                                                 unsigned short* __restrict__ hs,
                                                 float* __restrict__ tail,
                                                 unsigned* __restrict__ flags) {
  int p = blockIdx.x;
  int j0 = p * 16;
  int tid = threadIdx.x;
  int wave = tid >> 6, lane = tid & 63;
  int m = wave >> 1, n = wave & 1;   // m: gate 0..3, n: batch half
  int lr = lane & 15, ko = lane >> 4;

  __shared__ float gates[64][36];    // [gate*16+jj][b], padded stride 36 (2-way max)

  // persistent A-fragments: W_hh row m*H + j0 + lr, k = ks*32 + ko*8 .. +8
  short8 aW[32];
  {
    const float* wr = whh + (size_t)(m * HH + j0 + lr) * HH + ko * 8;
#pragma unroll
    for (int ks = 0; ks < 32; ++ks) {
      f32x4 lo = *(const f32x4*)(wr + ks * 32);
      f32x4 hi = *(const f32x4*)(wr + ks * 32 + 4);
      aW[ks] = pack8(lo, hi);
    }
  }

  // update-phase identity: thread owns (b, jj)
  int jj = tid & 15, b = tid >> 4;
  float c = c0[b * HH + j0 + jj];
  {
    // initial h publish (buffer 0) via the coherent path
    unsigned hv = f2bf(h0[b * HH + j0 + jj]);
    unsigned up = __shfl_down(hv, 1);
    if (!(jj & 1)) {
      size_t e = (size_t)b * HH + j0 + jj;
      __hip_atomic_store((unsigned*)hbuf + (e >> 1), hv | (up << 16),
                         __ATOMIC_RELAXED, __HIP_MEMORY_SCOPE_AGENT);
    }
  }
  gridbar(flags, p, 1u, tid);

  // xg register prefetch (t = 0)
  const unsigned short* xp = xg + (size_t)(j0 + jj) * BB + b;
  unsigned short xi = xp[0];
  unsigned short xf = xp[(size_t)HH * BB];
  unsigned short xc = xp[(size_t)2 * HH * BB];
  unsigned short xo = xp[(size_t)3 * HH * BB];

  for (int t = 0; t < TT; ++t) {
    // ---- GEMM: gates[m*16+i][n*16+j] = sum_k W_hh[m*H+j0+i][k] * h[n*16+j][k]
    size_t elem = (size_t)(t & 1) * BB * HH + (size_t)(n * 16 + lr) * HH + ko * 8;
    unsigned long long* hq = (unsigned long long*)(hbuf + elem);
    f32x4 acc0 = {0.f, 0.f, 0.f, 0.f}, acc1 = {0.f, 0.f, 0.f, 0.f};
#pragma unroll
    for (int ks = 0; ks < 32; ks += 2) {
      Q2S u0, u1;
      u0.q[0] = __hip_atomic_load(hq + ks * 8 + 0, __ATOMIC_RELAXED, __HIP_MEMORY_SCOPE_AGENT);
      u0.q[1] = __hip_atomic_load(hq + ks * 8 + 1, __ATOMIC_RELAXED, __HIP_MEMORY_SCOPE_AGENT);
      u1.q[0] = __hip_atomic_load(hq + ks * 8 + 8, __ATOMIC_RELAXED, __HIP_MEMORY_SCOPE_AGENT);
      u1.q[1] = __hip_atomic_load(hq + ks * 8 + 9, __ATOMIC_RELAXED, __HIP_MEMORY_SCOPE_AGENT);
      acc0 = __builtin_amdgcn_mfma_f32_16x16x32_bf16(aW[ks], u0.s, acc0, 0, 0, 0);
      acc1 = __builtin_amdgcn_mfma_f32_16x16x32_bf16(aW[ks + 1], u1.s, acc1, 0, 0, 0);
    }
    f32x4 acc = acc0 + acc1;
    {
      int r0 = m * 16 + ko * 4, cD = n * 16 + lr;
      gates[r0 + 0][cD] = acc[0];
      gates[r0 + 1][cD] = acc[1];
      gates[r0 + 2][cD] = acc[2];
      gates[r0 + 3][cD] = acc[3];
    }

    // prefetch next step's xg into regs (overlaps with LDS/update; values live
    // in registers across the barrier)
    unsigned short nxi = 0, nxf = 0, nxc = 0, nxo = 0;
    if (t < TT - 1) {
      const unsigned short* q = xp + (size_t)(t + 1) * GG * BB;
      nxi = q[0];
      nxf = q[(size_t)HH * BB];
      nxc = q[(size_t)2 * HH * BB];
      nxo = q[(size_t)3 * HH * BB];
    }
    __syncthreads();

    // ---- update: gate order [i, f, g, o]
    float gi = gates[jj][b]      + bf2f(xi);
    float gf = gates[16 + jj][b] + bf2f(xf);
    float gc = gates[32 + jj][b] + bf2f(xc);
    float go = gates[48 + jj][b] + bf2f(xo);
    float ig = 1.f / (1.f + __expf(-gi));
    float fg = 1.f / (1.f + __expf(-gf));
    float ag = fabsf(gc), eg = __expf(-2.f * ag);
    float tg = (1.f - eg) / (1.f + eg); tg = gc < 0.f ? -tg : tg;
    float og = 1.f / (1.f + __expf(-go));
    c = fg * c + ig * tg;
    float ac = fabsf(c), ec = __expf(-2.f * ac);
    float tc = (1.f - ec) / (1.f + ec); tc = c < 0.f ? -tc : tc;
    float h = og * tc;
    unsigned short h16 = f2bf(h);
    {
      unsigned hv = h16;
      unsigned up = __shfl_down(hv, 1);
      if (!(jj & 1)) {
        size_t e = (size_t)((t + 1) & 1) * BB * HH + (size_t)b * HH + j0 + jj;
        __hip_atomic_store((unsigned*)hbuf + (e >> 1), hv | (up << 16),
                           __ATOMIC_RELAXED, __HIP_MEMORY_SCOPE_AGENT);
      }
    }
    hs[((size_t)b * TT + t) * HH + j0 + jj] = h16;
    if (t == TT - 1) {
      tail[b * HH + j0 + jj] = h;             // hT
      tail[BB * HH + b * HH + j0 + jj] = c;   // cT
    }
    xi = nxi; xf = nxf; xc = nxc; xo = nxo;
    if (t < TT - 1) gridbar(flags, p, (unsigned)(t + 2), tid);
  }
}

// ---------- out[m][n] = dot(hs[m][:], fc_W[n][:]) + fc_b[n] ----------
// grid (256, 4), block tile 64M x 64N, wave = 16M x 64N (4 N-tiles), K=1024
__global__ __launch_bounds__(256) void k_fc(const unsigned short* __restrict__ hs,
                                            const unsigned short* __restrict__ fw,
                                            const float* __restrict__ fb,
                                            float* __restrict__ out) {
  int mb = blockIdx.x * 64, nb = blockIdx.y * 64;
  int wave = threadIdx.x >> 6, lane = threadIdx.x & 63;
  int lr = lane & 15, ko = lane >> 4;
  int rowA = mb + wave * 16 + lr;
  f32x4 acc[4] = {{0, 0, 0, 0}, {0, 0, 0, 0}, {0, 0, 0, 0}, {0, 0, 0, 0}};
#pragma unroll 8
  for (int ks = 0; ks < 32; ++ks) {
    int k = ks * 32 + ko * 8;
    short8 a = *(const short8*)(hs + (size_t)rowA * HH + k);
#pragma unroll
    for (int nt = 0; nt < 4; ++nt) {
      short8 bb = *(const short8*)(fw + (size_t)(nb + nt * 16 + lr) * HH + k);
      acc[nt] = __builtin_amdgcn_mfma_f32_16x16x32_bf16(a, bb, acc[nt], 0, 0, 0);
    }
  }
  int rD = mb + wave * 16 + ko * 4;
#pragma unroll
  for (int nt = 0; nt < 4; ++nt) {
    int col = nb + nt * 16 + lr;
    float bias = fb[col];
#pragma unroll
    for (int q = 0; q < 4; ++q)
      out[(size_t)(rD + q) * OO + col] = acc[nt][q] + bias;
  }
}

extern "C" void kernel_launch(void* const* d_in, const int* in_sizes, int n_in,
                              void* d_out, int out_size, void* d_ws, size_t ws_size,
                              hipStream_t stream) {
  (void)in_sizes; (void)n_in; (void)out_size; (void)ws_size;
  const float* x   = (const float*)d_in[0];
  const float* h0  = (const float*)d_in[1];
  const float* c0  = (const float*)d_in[2];
  const float* wih = (const float*)d_in[3];
  const float* whh = (const float*)d_in[4];
  const float* bih = (const float*)d_in[5];
  const float* bhh = (const float*)d_in[6];
  const float* fcw = (const float*)d_in[7];
  const float* fcb = (const float*)d_in[8];
  float* out = (float*)d_out;

  // workspace carve (total ~181 MB)
  char* w = (char*)d_ws;
  unsigned short* xg   = (unsigned short*)w; w += (size_t)TT * GG * BB * 2;  // 128 MiB  xg[t][g][b]
  unsigned short* hsb  = (unsigned short*)w; w += (size_t)BB * TT * HH * 2;  //  32 MiB  hs[b][t][j]
  unsigned short* xb   = (unsigned short*)w; w += (size_t)BB * TT * II * 2;  //  16 MiB  x bf16
  unsigned short* wbb  = (unsigned short*)w; w += (size_t)GG * II * 2;       //   4 MiB  W_ih bf16
  unsigned short* fwb  = (unsigned short*)w; w += (size_t)OO * HH * 2;       // 512 KiB  fc_W bf16
  unsigned short* hbuf = (unsigned short*)w; w += (size_t)2 * BB * HH * 2;   // 128 KiB  h double buffer
  unsigned* flags      = (unsigned*)w;       w += 4096;

  hipMemsetAsync(flags, 0, 256 * sizeof(unsigned), stream);
  k_convert<<<(BB * TT * II / 8) / 256, 256, 0, stream>>>(x, xb, BB * TT * II / 8);
  k_convert<<<(GG * II / 8) / 256, 256, 0, stream>>>(wih, wbb, GG * II / 8);
  k_convert<<<(OO * HH / 8) / 256, 256, 0, stream>>>(fcw, fwb, OO * HH / 8);
  k_xg<<<dim3(64, TT), 256, 0, stream>>>(xb, wbb, bih, bhh, xg);
  k_scan<<<64, 512, 0, stream>>>(whh, xg, h0, c0, hbuf, hsb,
                                 out + (size_t)BB * TT * OO, flags);
  k_fc<<<dim3(BB * TT / 64, OO / 64), 256, 0, stream>>>(hsb, fwb, fcb, out);
}

// Round 6
// 6100.817 us; speedup vs baseline: 1.6248x; 1.6248x over previous
//
#include <hip/hip_runtime.h>
#include <cstdint>
#include <cstddef>

// Problem dims
#define TT 512   // timesteps
#define BB 32    // batch
#define II 512   // input dim
#define HH 1024  // hidden dim
#define OO 256   // output dim
#define GG 4096  // 4*H

typedef __attribute__((ext_vector_type(8))) short short8;
typedef __attribute__((ext_vector_type(4))) float f32x4;

__device__ __forceinline__ unsigned short f2bf(float f) {
  unsigned u = __float_as_uint(f);
  u = (u + 0x7FFFu + ((u >> 16) & 1u)) >> 16;  // RNE truncation (inputs finite)
  return (unsigned short)u;
}
__device__ __forceinline__ float bf2f(unsigned short s) {
  return __uint_as_float(((unsigned)s) << 16);
}
__device__ __forceinline__ short8 pack8(f32x4 lo, f32x4 hi) {
  short8 v;
  v[0] = (short)f2bf(lo[0]); v[1] = (short)f2bf(lo[1]);
  v[2] = (short)f2bf(lo[2]); v[3] = (short)f2bf(lo[3]);
  v[4] = (short)f2bf(hi[0]); v[5] = (short)f2bf(hi[1]);
  v[6] = (short)f2bf(hi[2]); v[7] = (short)f2bf(hi[3]);
  return v;
}

// ---------- fp32 -> bf16 bulk convert (8 elems/thread) ----------
__global__ __launch_bounds__(256) void k_convert(const float* __restrict__ in,
                                                 unsigned short* __restrict__ out,
                                                 int n8) {
  int i = blockIdx.x * 256 + threadIdx.x;
  if (i >= n8) return;
  const f32x4* p = (const f32x4*)in + (size_t)i * 2;
  f32x4 a = p[0], b = p[1];
  *((short8*)out + i) = pack8(a, b);
}

// ---------- xg[t][g][b] = dot(x[b][t][:], W_ih[g][:]) + b_ih[g] + b_hh[g] ----------
// grid (64 gtiles, 512 t), 256 thr = 4 waves; wave = 16 g-rows x 32 b (2 N-tiles), K=512
__global__ __launch_bounds__(256) void k_xg(const unsigned short* __restrict__ xb,
                                            const unsigned short* __restrict__ wb,
                                            const float* __restrict__ bih,
                                            const float* __restrict__ bhh,
                                            unsigned short* __restrict__ xg) {
  int t = blockIdx.y;
  int g0 = blockIdx.x * 64;
  int wave = threadIdx.x >> 6, lane = threadIdx.x & 63;
  int lr = lane & 15, ko = lane >> 4;
  int rowA = g0 + wave * 16 + lr;        // W_ih row this lane loads (A row)
  int rD = g0 + wave * 16 + ko * 4;      // first D row this lane owns
  f32x4 bias = *(const f32x4*)(bih + rD);
  bias += *(const f32x4*)(bhh + rD);
  f32x4 acc0 = bias, acc1 = bias;
  const short8* arow = (const short8*)(wb + (size_t)rowA * II);
#pragma unroll
  for (int ks = 0; ks < 16; ++ks) {
    int k = ks * 32 + ko * 8;
    short8 a = arow[k >> 3];
    short8 b0 = *(const short8*)(xb + ((size_t)lr * TT + t) * II + k);
    short8 b1 = *(const short8*)(xb + ((size_t)(lr + 16) * TT + t) * II + k);
    acc0 = __builtin_amdgcn_mfma_f32_16x16x32_bf16(a, b0, acc0, 0, 0, 0);
    acc1 = __builtin_amdgcn_mfma_f32_16x16x32_bf16(a, b1, acc1, 0, 0, 0);
  }
  size_t base = (size_t)t * GG * BB;
#pragma unroll
  for (int q = 0; q < 4; ++q) {
    xg[base + (size_t)(rD + q) * BB + lr] = f2bf(acc0[q]);
    xg[base + (size_t)(rD + q) * BB + 16 + lr] = f2bf(acc1[q]);
  }
}

// ---------- grid barrier: no-wbl2 version (deconfounding experiment) ----------
// Writer side: h published via relaxed sc1 atomic stores (write-through to the
// coherence point) -> explicit vmcnt(0) drain orders them before the RELAXED
// flag store. No release fence => no buffer_wbl2 L2-writeback walk anywhere.
// Reader side: relaxed poll; then ONE acquire fence (wave 0 only: one
// buffer_inv covering this CU's L1 + this XCD's L2) so the subsequent PLAIN
// wide hbuf loads cannot hit stale lines.
__device__ __forceinline__ void gridbar(unsigned* flags, int p, unsigned gen, int tid) {
  asm volatile("s_waitcnt vmcnt(0)" ::: "memory");
  __syncthreads();
  if (tid == 0)
    __hip_atomic_store(flags + p, gen, __ATOMIC_RELAXED, __HIP_MEMORY_SCOPE_AGENT);
  if (tid < 64) {
    int it = 0;
    for (;;) {
      unsigned v = __hip_atomic_load(flags + tid, __ATOMIC_RELAXED, __HIP_MEMORY_SCOPE_AGENT);
      if (v >= gen) break;
      __builtin_amdgcn_s_sleep(1);
      if (++it > (1 << 24)) break;  // hang-safety: break instead of deadlock
    }
    __builtin_amdgcn_fence(__ATOMIC_ACQUIRE, "agent");  // single L1+L2 inv
  }
  asm volatile("" ::: "memory");
  __syncthreads();
}

// ---------- persistent LSTM scan ----------
// 64 blocks x 512 thr (8 waves). Block p owns h-cols j0=p*16..+15 (64 W_hh rows).
// Wave (m = gate, n = batch-half) keeps its W_hh A-frags in registers (32x short8).
// Per step: B-frags (h bf16) via PLAIN coalesced short8 loads (fresh after the
// barrier's inv), 32 mfma/wave, gate exchange via LDS, fp32 activations, h
// published via packed relaxed sc1 atomic dword stores. One barrier/step.
__global__ __launch_bounds__(512, 2) void k_scan(const float* __restrict__ whh,
                                                 const unsigned short* __restrict__ xg,
                                                 const float* __restrict__ h0,
                                                 const float* __restrict__ c0,
                                                 unsigned short* __restrict__ hbuf,
                                                 unsigned short* __restrict__ hs,
                                                 float* __restrict__ tail,
                                                 unsigned* __restrict__ flags) {
  int p = blockIdx.x;
  int j0 = p * 16;
  int tid = threadIdx.x;
  int wave = tid >> 6, lane = tid & 63;
  int m = wave >> 1, n = wave & 1;   // m: gate 0..3, n: batch half
  int lr = lane & 15, ko = lane >> 4;

  __shared__ float gates[64][36];    // [gate*16+jj][b], padded stride 36 (2-way max)

  // persistent A-fragments: W_hh row m*H + j0 + lr, k = ks*32 + ko*8 .. +8
  short8 aW[32];
  {
    const float* wr = whh + (size_t)(m * HH + j0 + lr) * HH + ko * 8;
#pragma unroll
    for (int ks = 0; ks < 32; ++ks) {
      f32x4 lo = *(const f32x4*)(wr + ks * 32);
      f32x4 hi = *(const f32x4*)(wr + ks * 32 + 4);
      aW[ks] = pack8(lo, hi);
    }
  }

  // update-phase identity: thread owns (b, jj)
  int jj = tid & 15, b = tid >> 4;
  float c = c0[b * HH + j0 + jj];
  {
    // initial h publish (buffer 0) via the coherent path
    unsigned hv = f2bf(h0[b * HH + j0 + jj]);
    unsigned up = __shfl_down(hv, 1);
    if (!(jj & 1)) {
      size_t e = (size_t)b * HH + j0 + jj;
      __hip_atomic_store((unsigned*)hbuf + (e >> 1), hv | (up << 16),
                         __ATOMIC_RELAXED, __HIP_MEMORY_SCOPE_AGENT);
    }
  }
  gridbar(flags, p, 1u, tid);

  // xg register prefetch (t = 0)
  const unsigned short* xp = xg + (size_t)(j0 + jj) * BB + b;
  unsigned short xi = xp[0];
  unsigned short xf = xp[(size_t)HH * BB];
  unsigned short xc = xp[(size_t)2 * HH * BB];
  unsigned short xo = xp[(size_t)3 * HH * BB];

  for (int t = 0; t < TT; ++t) {
    // ---- GEMM: gates[m*16+i][n*16+j] = sum_k W_hh[m*H+j0+i][k] * h[n*16+j][k]
    const unsigned short* hb =
        hbuf + (size_t)(t & 1) * BB * HH + (size_t)(n * 16 + lr) * HH + ko * 8;
    f32x4 acc0 = {0.f, 0.f, 0.f, 0.f}, acc1 = {0.f, 0.f, 0.f, 0.f};
#pragma unroll
    for (int ks = 0; ks < 32; ks += 2) {
      short8 bf0 = *(const short8*)(hb + ks * 32);
      short8 bf1 = *(const short8*)(hb + ks * 32 + 32);
      acc0 = __builtin_amdgcn_mfma_f32_16x16x32_bf16(aW[ks], bf0, acc0, 0, 0, 0);
      acc1 = __builtin_amdgcn_mfma_f32_16x16x32_bf16(aW[ks + 1], bf1, acc1, 0, 0, 0);
    }
    f32x4 acc = acc0 + acc1;
    {
      int r0 = m * 16 + ko * 4, cD = n * 16 + lr;
      gates[r0 + 0][cD] = acc[0];
      gates[r0 + 1][cD] = acc[1];
      gates[r0 + 2][cD] = acc[2];
      gates[r0 + 3][cD] = acc[3];
    }

    // prefetch next step's xg into regs (overlaps with LDS/update; values live
    // in registers across the barrier)
    unsigned short nxi = 0, nxf = 0, nxc = 0, nxo = 0;
    if (t < TT - 1) {
      const unsigned short* q = xp + (size_t)(t + 1) * GG * BB;
      nxi = q[0];
      nxf = q[(size_t)HH * BB];
      nxc = q[(size_t)2 * HH * BB];
      nxo = q[(size_t)3 * HH * BB];
    }
    __syncthreads();

    // ---- update: gate order [i, f, g, o]
    float gi = gates[jj][b]      + bf2f(xi);
    float gf = gates[16 + jj][b] + bf2f(xf);
    float gc = gates[32 + jj][b] + bf2f(xc);
    float go = gates[48 + jj][b] + bf2f(xo);
    float ig = 1.f / (1.f + __expf(-gi));
    float fg = 1.f / (1.f + __expf(-gf));
    float ag = fabsf(gc), eg = __expf(-2.f * ag);
    float tg = (1.f - eg) / (1.f + eg); tg = gc < 0.f ? -tg : tg;
    float og = 1.f / (1.f + __expf(-go));
    c = fg * c + ig * tg;
    float ac = fabsf(c), ec = __expf(-2.f * ac);
    float tc = (1.f - ec) / (1.f + ec); tc = c < 0.f ? -tc : tc;
    float h = og * tc;
    unsigned short h16 = f2bf(h);
    {
      unsigned hv = h16;
      unsigned up = __shfl_down(hv, 1);
      if (!(jj & 1)) {
        size_t e = (size_t)((t + 1) & 1) * BB * HH + (size_t)b * HH + j0 + jj;
        __hip_atomic_store((unsigned*)hbuf + (e >> 1), hv | (up << 16),
                           __ATOMIC_RELAXED, __HIP_MEMORY_SCOPE_AGENT);
      }
    }
    hs[((size_t)b * TT + t) * HH + j0 + jj] = h16;
    if (t == TT - 1) {
      tail[b * HH + j0 + jj] = h;             // hT
      tail[BB * HH + b * HH + j0 + jj] = c;   // cT
    }
    xi = nxi; xf = nxf; xc = nxc; xo = nxo;
    if (t < TT - 1) gridbar(flags, p, (unsigned)(t + 2), tid);
  }
}

// ---------- out[m][n] = dot(hs[m][:], fc_W[n][:]) + fc_b[n] ----------
// grid (256, 4), block tile 64M x 64N, wave = 16M x 64N (4 N-tiles), K=1024
__global__ __launch_bounds__(256) void k_fc(const unsigned short* __restrict__ hs,
                                            const unsigned short* __restrict__ fw,
                                            const float* __restrict__ fb,
                                            float* __restrict__ out) {
  int mb = blockIdx.x * 64, nb = blockIdx.y * 64;
  int wave = threadIdx.x >> 6, lane = threadIdx.x & 63;
  int lr = lane & 15, ko = lane >> 4;
  int rowA = mb + wave * 16 + lr;
  f32x4 acc[4] = {{0, 0, 0, 0}, {0, 0, 0, 0}, {0, 0, 0, 0}, {0, 0, 0, 0}};
#pragma unroll 8
  for (int ks = 0; ks < 32; ++ks) {
    int k = ks * 32 + ko * 8;
    short8 a = *(const short8*)(hs + (size_t)rowA * HH + k);
#pragma unroll
    for (int nt = 0; nt < 4; ++nt) {
      short8 bb = *(const short8*)(fw + (size_t)(nb + nt * 16 + lr) * HH + k);
      acc[nt] = __builtin_amdgcn_mfma_f32_16x16x32_bf16(a, bb, acc[nt], 0, 0, 0);
    }
  }
  int rD = mb + wave * 16 + ko * 4;
#pragma unroll
  for (int nt = 0; nt < 4; ++nt) {
    int col = nb + nt * 16 + lr;
    float bias = fb[col];
#pragma unroll
    for (int q = 0; q < 4; ++q)
      out[(size_t)(rD + q) * OO + col] = acc[nt][q] + bias;
  }
}

extern "C" void kernel_launch(void* const* d_in, const int* in_sizes, int n_in,
                              void* d_out, int out_size, void* d_ws, size_t ws_size,
                              hipStream_t stream) {
  (void)in_sizes; (void)n_in; (void)out_size; (void)ws_size;
  const float* x   = (const float*)d_in[0];
  const float* h0  = (const float*)d_in[1];
  const float* c0  = (const float*)d_in[2];
  const float* wih = (const float*)d_in[3];
  const float* whh = (const float*)d_in[4];
  const float* bih = (const float*)d_in[5];
  const float* bhh = (const float*)d_in[6];
  const float* fcw = (const float*)d_in[7];
  const float* fcb = (const float*)d_in[8];
  float* out = (float*)d_out;

  // workspace carve (total ~181 MB)
  char* w = (char*)d_ws;
  unsigned short* xg   = (unsigned short*)w; w += (size_t)TT * GG * BB * 2;  // 128 MiB  xg[t][g][b]
  unsigned short* hsb  = (unsigned short*)w; w += (size_t)BB * TT * HH * 2;  //  32 MiB  hs[b][t][j]
  unsigned short* xb   = (unsigned short*)w; w += (size_t)BB * TT * II * 2;  //  16 MiB  x bf16
  unsigned short* wbb  = (unsigned short*)w; w += (size_t)GG * II * 2;       //   4 MiB  W_ih bf16
  unsigned short* fwb  = (unsigned short*)w; w += (size_t)OO * HH * 2;       // 512 KiB  fc_W bf16
  unsigned short* hbuf = (unsigned short*)w; w += (size_t)2 * BB * HH * 2;   // 128 KiB  h double buffer
  unsigned* flags      = (unsigned*)w;       w += 4096;

  hipMemsetAsync(flags, 0, 256 * sizeof(unsigned), stream);
  k_convert<<<(BB * TT * II / 8) / 256, 256, 0, stream>>>(x, xb, BB * TT * II / 8);
  k_convert<<<(GG * II / 8) / 256, 256, 0, stream>>>(wih, wbb, GG * II / 8);
  k_convert<<<(OO * HH / 8) / 256, 256, 0, stream>>>(fcw, fwb, OO * HH / 8);
  k_xg<<<dim3(64, TT), 256, 0, stream>>>(xb, wbb, bih, bhh, xg);
  k_scan<<<64, 512, 0, stream>>>(whh, xg, h0, c0, hbuf, hsb,
                                 out + (size_t)BB * TT * OO, flags);
  k_fc<<<dim3(BB * TT / 64, OO / 64), 256, 0, stream>>>(hsb, fwb, fcb, out);
}